// Round 14
// baseline (299.361 us; speedup 1.0000x reference)
//
#include <hip/hip_runtime.h>
#include <stdint.h>

#define Bd 4
#define Cd 256
#define Hd 256
#define Wd 256
#define HW 65536
#define CM 64
#define KK 9
#define CG 32   // channels per wave in agg

// ---------------- Kernel A as MFMA GEMM: comp[o,s] = sum_c w[o,c] * x[c,s]
// M=64 (o), K=256 (c), N=262144 (b,s). bf16 inputs, fp32 accumulate.
// FROZEN after R10/R11 nulls: direct-global float4 B-path + LDS-swizzled w +
// reg double-buffer sits at the strided-read BW plateau.

typedef __attribute__((ext_vector_type(8))) short bf16x8;
typedef __attribute__((ext_vector_type(4))) float f32x4;

__device__ __forceinline__ uint32_t pkbf(float lo, float hi) {
    uint32_t r;
    asm("v_cvt_pk_bf16_f32 %0, %1, %2" : "=v"(r) : "v"(lo), "v"(hi));
    return r;
}
__device__ __forceinline__ float bf2f(uint32_t u) {   // low 16 bits -> f32
    return __uint_as_float(u << 16);
}

union BF8 { uint32_t u[4]; bf16x8 v; };

__device__ __forceinline__ void loadB(const float* __restrict__ px, int ks,
                                      float4 (&buf)[8]) {
#pragma unroll
    for (int j = 0; j < 8; ++j)
        buf[j] = *(const float4*)(px + (size_t)(ks * 32 + j) * HW);
}

__device__ __forceinline__ void stepMFMA(const float4 (&buf)[8],
                                         const short (*ws)[256], int ks,
                                         int l15, int lhi, int l7,
                                         f32x4 (&acc)[4][4]) {
    BF8 bn[4];
    bn[0].u[0] = pkbf(buf[0].x, buf[1].x);
    bn[0].u[1] = pkbf(buf[2].x, buf[3].x);
    bn[0].u[2] = pkbf(buf[4].x, buf[5].x);
    bn[0].u[3] = pkbf(buf[6].x, buf[7].x);
    bn[1].u[0] = pkbf(buf[0].y, buf[1].y);
    bn[1].u[1] = pkbf(buf[2].y, buf[3].y);
    bn[1].u[2] = pkbf(buf[4].y, buf[5].y);
    bn[1].u[3] = pkbf(buf[6].y, buf[7].y);
    bn[2].u[0] = pkbf(buf[0].z, buf[1].z);
    bn[2].u[1] = pkbf(buf[2].z, buf[3].z);
    bn[2].u[2] = pkbf(buf[4].z, buf[5].z);
    bn[2].u[3] = pkbf(buf[6].z, buf[7].z);
    bn[3].u[0] = pkbf(buf[0].w, buf[1].w);
    bn[3].u[1] = pkbf(buf[2].w, buf[3].w);
    bn[3].u[2] = pkbf(buf[4].w, buf[5].w);
    bn[3].u[3] = pkbf(buf[6].w, buf[7].w);
#pragma unroll
    for (int m = 0; m < 4; ++m) {
        int gg = ((ks << 2) + lhi) ^ l7;                 // swizzled granule col
        bf16x8 af = *(const bf16x8*)&ws[m * 16 + l15][gg << 3];
        acc[m][0] = __builtin_amdgcn_mfma_f32_16x16x32_bf16(af, bn[0].v, acc[m][0], 0, 0, 0);
        acc[m][1] = __builtin_amdgcn_mfma_f32_16x16x32_bf16(af, bn[1].v, acc[m][1], 0, 0, 0);
        acc[m][2] = __builtin_amdgcn_mfma_f32_16x16x32_bf16(af, bn[2].v, acc[m][2], 0, 0, 0);
        acc[m][3] = __builtin_amdgcn_mfma_f32_16x16x32_bf16(af, bn[3].v, acc[m][3], 0, 0, 0);
    }
}

__global__ __launch_bounds__(256, 2) void compress_kernel(
    const float* __restrict__ x, const float* __restrict__ w_comp,
    unsigned short* __restrict__ comp)
{
    __shared__ short ws[CM][256];   // bf16 w, swizzled: granule g stored at g^(o&7)

    int tid = threadIdx.x;
    {   // stage w: thread t -> row o=t>>2, k-range (t&3)*64..+63 (coalesced)
        int o  = tid >> 2;
        int k0 = (tid & 3) << 6;
        const float* wr = w_comp + o * Cd + k0;
        int xr = o & 7;
#pragma unroll
        for (int gi = 0; gi < 8; ++gi) {
            float4 a = *(const float4*)(wr + gi * 8);
            float4 c = *(const float4*)(wr + gi * 8 + 4);
            BF8 g;
            g.u[0] = pkbf(a.x, a.y); g.u[1] = pkbf(a.z, a.w);
            g.u[2] = pkbf(c.x, c.y); g.u[3] = pkbf(c.z, c.w);
            int gg = ((k0 >> 3) + gi) ^ xr;
            *(bf16x8*)&ws[o][gg << 3] = g.v;
        }
    }
    __syncthreads();

    int lane = tid & 63;
    int wv   = tid >> 6;
    int blk  = blockIdx.x;            // 1024 blocks: [b(4)][s-tile(256)]
    int b    = blk >> 8;
    int s0   = ((blk & 255) << 8) + (wv << 6);   // wave: 64 s, all 64 o
    int l15  = lane & 15, lhi = lane >> 4, l7 = lane & 7;

    // lane's B data: x[b][ks*32 + lhi*8 + j][s0 + 4*l15 + {0..3}] (one float4)
    const float* px = x + (size_t)b * Cd * HW + (size_t)(lhi * 8) * HW + s0 + 4 * l15;

    f32x4 acc[4][4];
    f32x4 zz = {0.f, 0.f, 0.f, 0.f};
#pragma unroll
    for (int m = 0; m < 4; ++m)
#pragma unroll
        for (int n = 0; n < 4; ++n) acc[m][n] = zz;

    float4 pa[8], pb[8];
    loadB(px, 0, pa);
    for (int ks = 0; ks < 8; ks += 2) {
        loadB(px, ks + 1, pb);                       // prefetch odd step
        stepMFMA(pa, ws, ks, l15, lhi, l7, acc);     // consume even step
        if (ks + 2 < 8) loadB(px, ks + 2, pa);       // prefetch next even
        stepMFMA(pb, ws, ks + 1, l15, lhi, l7, acc); // consume odd step
    }

    // D layout (m89-verified): col = lane&15, row = (lane>>4)*4 + reg.
    // n-perm: col c of frag n -> s = s0 + 4c + n, so acc[m][0..3][r] are 4
    // adjacent s -> two packed bf16 u32 = one 8B store per (m,r).
    unsigned short* ob = comp + (size_t)b * CM * HW + s0 + 4 * l15;
#pragma unroll
    for (int m = 0; m < 4; ++m)
#pragma unroll
        for (int r = 0; r < 4; ++r) {
            uint2 pk;
            pk.x = pkbf(acc[m][0][r], acc[m][1][r]);
            pk.y = pkbf(acc[m][2][r], acc[m][3][r]);
            *(uint2*)&ob[(size_t)(m * 16 + lhi * 4 + r) * HW] = pk;
        }
}

// ---------------- tiny one-shot transpose: w_gen[t][c][p] -> wt_t[c][t*9+p]
// 21 KB copy; lets kwgen read per-c weights as ONE contiguous scalar block.
__global__ __launch_bounds__(256) void wtr_kernel(
    const float* __restrict__ w_gen, float* __restrict__ wt_t)
{
    int i = blockIdx.x * 256 + threadIdx.x;   // 5184 total
    if (i < KK * CM * 9) {
        int t = i / (CM * 9);
        int r = i - t * (CM * 9);
        int c = r / 9;
        int p = r - c * 9;
        wt_t[c * 81 + t * 9 + p] = w_gen[i];
    }
}

// ---------------- Kernel B v4 (bf16 comp input): 3x3 conv + bias + softmax over 9 taps
// R14: weights moved off the LDS pipe. R13's wlds[c][t][p] cost 81 wave-uniform
// ds_reads per channel (~470 LDS-pipe cyc/c vs 324 VALU cyc/c -> LDS-bound).
// Weights are uniform -> scalar path: read wt_t + c*81 via a wave-uniform pointer
// (compiler emits clustered s_load_dwordx16 on the scalar pipe; FMA takes the
// SGPR operand directly). Same values, same FMA order -> bit-identical.
__global__ __launch_bounds__(512, 2) void kwgen_kernel(
    const unsigned short* __restrict__ comp, const float* __restrict__ wt_t,
    const float* __restrict__ b_gen, float* __restrict__ kw)
{
    int lane = threadIdx.x & 63;
    int wid  = threadIdx.x >> 6;      // 0..7
    int half = wid & 1;               // which half-row
    // XCD-chunked swizzle (T1, bijective: 256 % 8 == 0)
    int blk  = (blockIdx.x & 7) * 32 + (blockIdx.x >> 3);   // 256 blocks: [b(4)][h-quad(64)]
    int b    = blk >> 6;
    int h    = ((blk & 63) << 2) + (wid >> 1);
    int w0   = (half << 7) + (lane << 1);     // first of 2 positions (even)
    bool hmv = h > 0, hpv = h < Hd - 1;

    float accv[KK][2];
#pragma unroll
    for (int t = 0; t < KK; ++t) { float bg = b_gen[t]; accv[t][0] = bg; accv[t][1] = bg; }

    const unsigned short* cb = comp + (size_t)b * CM * HW + h * Wd;
    for (int c = 0; c < CM; ++c) {
        const float* wc = wt_t + c * 81;          // wave-uniform -> s_load stream
        const unsigned short* row = cb + (size_t)c * HW;
        const unsigned short* rm  = row - Wd;
        const unsigned short* rp  = row + Wd;
        uint32_t amu = hmv ? *(const uint32_t*)(rm + w0) : 0u;
        uint32_t acu = *(const uint32_t*)(row + w0);
        uint32_t apu = hpv ? *(const uint32_t*)(rp + w0) : 0u;
        float amx = bf2f(amu), amy = bf2f(amu >> 16);
        float acx = bf2f(acu), acy = bf2f(acu >> 16);
        float apx = bf2f(apu), apy = bf2f(apu >> 16);
        float Lm = __shfl_up(amy, 1), Lc = __shfl_up(acy, 1), Lp = __shfl_up(apy, 1);
        float Rm = __shfl_down(amx, 1), Rc = __shfl_down(acx, 1), Rp = __shfl_down(apx, 1);
        if (lane == 0) {
            if (w0 == 0) { Lm = 0.f; Lc = 0.f; Lp = 0.f; }
            else {
                Lm = hmv ? bf2f(rm[w0 - 1]) : 0.f;
                Lc = bf2f(row[w0 - 1]);
                Lp = hpv ? bf2f(rp[w0 - 1]) : 0.f;
            }
        }
        if (lane == 63) {
            int wr = w0 + 2;
            if (wr == Wd) { Rm = 0.f; Rc = 0.f; Rp = 0.f; }
            else {
                Rm = hmv ? bf2f(rm[wr]) : 0.f;
                Rc = bf2f(row[wr]);
                Rp = hpv ? bf2f(rp[wr]) : 0.f;
            }
        }
        float em[4] = {Lm, amx, amy, Rm};
        float ec[4] = {Lc, acx, acy, Rc};
        float ep[4] = {Lp, apx, apy, Rp};
#pragma unroll
        for (int t = 0; t < KK; ++t) {
            const float* wt = wc + t * 9;
#pragma unroll
            for (int j = 0; j < 2; ++j) {
                float a = accv[t][j];
                a = fmaf(em[j],     wt[0], a);
                a = fmaf(em[j + 1], wt[1], a);
                a = fmaf(em[j + 2], wt[2], a);
                a = fmaf(ec[j],     wt[3], a);
                a = fmaf(ec[j + 1], wt[4], a);
                a = fmaf(ec[j + 2], wt[5], a);
                a = fmaf(ep[j],     wt[6], a);
                a = fmaf(ep[j + 1], wt[7], a);
                a = fmaf(ep[j + 2], wt[8], a);
                accv[t][j] = a;
            }
        }
    }
    // softmax over the 9 taps, per position
    float inv[2];
#pragma unroll
    for (int j = 0; j < 2; ++j) {
        float m = accv[0][j];
#pragma unroll
        for (int t = 1; t < KK; ++t) m = fmaxf(m, accv[t][j]);
        float sum = 0.f;
#pragma unroll
        for (int t = 0; t < KK; ++t) { accv[t][j] = __expf(accv[t][j] - m); sum += accv[t][j]; }
        inv[j] = 1.f / sum;
    }
    float* ob = kw + (size_t)b * KK * HW + h * Wd + w0;
#pragma unroll
    for (int t = 0; t < KK; ++t) {
        float2 v = make_float2(accv[t][0] * inv[0], accv[t][1] * inv[1]);
        *(float2*)(ob + (size_t)t * HW) = v;
    }
}

// ---------------- Kernel C: view-scramble gather + hamming renorm + reflect aggregation
// Wave per (b, h, cgroup); XCD-chunked swizzle (T1, R13 win, kept).
__global__ __launch_bounds__(256) void agg_kernel(
    const float* __restrict__ x, const float* __restrict__ kw,
    float* __restrict__ out)
{
    const float HAM[9] = {0.0064f, 0.08f, 0.0064f,
                          0.08f,   1.0f,  0.08f,
                          0.0064f, 0.08f, 0.0064f};
    int lane = threadIdx.x & 63;
    int wid  = threadIdx.x >> 6;
    // XCD-chunked swizzle (T1, bijective: 2048 % 8 == 0)
    int blk  = (blockIdx.x & 7) * 256 + (blockIdx.x >> 3);  // [b(4)][cg(8)][h4(64)]
    int h4 = blk & 63;
    int cg = (blk >> 6) & 7;
    int b  = blk >> 9;
    int h  = h4 * 4 + wid;
    int hm = (h == 0) ? 1 : h - 1;
    int hp = (h == Hd - 1) ? Hd - 2 : h + 1;

    // load + hamming-normalize the 4 positions' tap weights (view-scramble gather)
    float wv[4][9];
    {
        const float4* kv = (const float4*)(kw + (size_t)b * KK * HW
                                              + (size_t)h * (Wd * 9) + lane * 36);
        float t[36];
#pragma unroll
        for (int i = 0; i < 9; ++i) {
            float4 v = kv[i];
            t[i * 4 + 0] = v.x; t[i * 4 + 1] = v.y;
            t[i * 4 + 2] = v.z; t[i * 4 + 3] = v.w;
        }
#pragma unroll
        for (int j = 0; j < 4; ++j) {
            float s = 1e-8f;
#pragma unroll
            for (int p = 0; p < 9; ++p) { float u = t[j * 9 + p] * HAM[p]; wv[j][p] = u; s += u; }
            float inv = 1.f / s;
#pragma unroll
            for (int p = 0; p < 9; ++p) wv[j][p] *= inv;
        }
    }

    const float* xb = x + (size_t)b * Cd * HW;
    float* ob = out + (size_t)b * Cd * HW;
    int c0 = cg * CG;
    for (int c = c0; c < c0 + CG; ++c) {
        const float* xc0 = xb + (size_t)c * HW;
        float4 am = ((const float4*)(xc0 + hm * Wd))[lane];
        float4 ac = ((const float4*)(xc0 + h  * Wd))[lane];
        float4 ap = ((const float4*)(xc0 + hp * Wd))[lane];
        float Lm = __shfl_up(am.w, 1), Lc = __shfl_up(ac.w, 1), Lp = __shfl_up(ap.w, 1);
        float Rm = __shfl_down(am.x, 1), Rc = __shfl_down(ac.x, 1), Rp = __shfl_down(ap.x, 1);
        if (lane == 0)  { Lm = am.y; Lc = ac.y; Lp = ap.y; }   // reflect w=-1 -> w=1
        if (lane == 63) { Rm = am.z; Rc = ac.z; Rp = ap.z; }   // reflect w=256 -> w=254
        float em[6] = {Lm, am.x, am.y, am.z, am.w, Rm};
        float ec[6] = {Lc, ac.x, ac.y, ac.z, ac.w, Rc};
        float ep[6] = {Lp, ap.x, ap.y, ap.z, ap.w, Rp};
        float o4[4];
#pragma unroll
        for (int j = 0; j < 4; ++j) {
            float agg = em[j] * wv[j][0];
            agg = fmaf(em[j + 1], wv[j][1], agg);
            agg = fmaf(em[j + 2], wv[j][2], agg);
            agg = fmaf(ec[j],     wv[j][3], agg);
            agg = fmaf(ec[j + 1], wv[j][4], agg);
            agg = fmaf(ec[j + 2], wv[j][5], agg);
            agg = fmaf(ep[j],     wv[j][6], agg);
            agg = fmaf(ep[j + 1], wv[j][7], agg);
            agg = fmaf(ep[j + 2], wv[j][8], agg);
            o4[j] = 2.f * ec[j + 1] - agg;
        }
        float4 o = {o4[0], o4[1], o4[2], o4[3]};
        ((float4*)(ob + (size_t)c * HW + h * Wd))[lane] = o;
    }
}

extern "C" void kernel_launch(void* const* d_in, const int* in_sizes, int n_in,
                              void* d_out, int out_size, void* d_ws, size_t ws_size,
                              hipStream_t stream) {
    const float* x      = (const float*)d_in[0];
    const float* w_comp = (const float*)d_in[1];
    const float* w_gen  = (const float*)d_in[2];
    const float* b_gen  = (const float*)d_in[3];
    float* out  = (float*)d_out;
    unsigned short* comp = (unsigned short*)d_ws;              // 4*64*65536 bf16 = 32 MiB
    float* kw = (float*)((char*)d_ws + (size_t)Bd * CM * HW * sizeof(unsigned short));
    float* wt_t = kw + (size_t)Bd * KK * HW;                   // 5184 floats = 20.7 KB

    wtr_kernel<<<21, 256, 0, stream>>>(w_gen, wt_t);
    compress_kernel<<<1024, 256, 0, stream>>>(x, w_comp, comp);
    kwgen_kernel<<<256, 512, 0, stream>>>(comp, wt_t, b_gen, kw);
    agg_kernel<<<2048, 256, 0, stream>>>(x, kw, out);
}

// Round 15
// 257.358 us; speedup vs baseline: 1.1632x; 1.1632x over previous
//
#include <hip/hip_runtime.h>
#include <stdint.h>

#define Bd 4
#define Cd 256
#define Hd 256
#define Wd 256
#define HW 65536
#define CM 64
#define KK 9
#define CG 32   // channels per wave in agg

// ---------------- Kernel A as MFMA GEMM: comp[o,s] = sum_c w[o,c] * x[c,s]
// M=64 (o), K=256 (c), N=262144 (b,s). bf16 inputs, fp32 accumulate.
// FROZEN after R10/R11 nulls: direct-global float4 B-path + LDS-swizzled w +
// reg double-buffer sits at the strided-read BW plateau; deeper queues (R10)
// and cvt_pk packing (R11) both null.

typedef __attribute__((ext_vector_type(8))) short bf16x8;
typedef __attribute__((ext_vector_type(4))) float f32x4;

__device__ __forceinline__ uint32_t pkbf(float lo, float hi) {
    uint32_t r;
    asm("v_cvt_pk_bf16_f32 %0, %1, %2" : "=v"(r) : "v"(lo), "v"(hi));
    return r;
}
__device__ __forceinline__ float bf2f(uint32_t u) {   // low 16 bits -> f32
    return __uint_as_float(u << 16);
}

union BF8 { uint32_t u[4]; bf16x8 v; };

__device__ __forceinline__ void loadB(const float* __restrict__ px, int ks,
                                      float4 (&buf)[8]) {
#pragma unroll
    for (int j = 0; j < 8; ++j)
        buf[j] = *(const float4*)(px + (size_t)(ks * 32 + j) * HW);
}

__device__ __forceinline__ void stepMFMA(const float4 (&buf)[8],
                                         const short (*ws)[256], int ks,
                                         int l15, int lhi, int l7,
                                         f32x4 (&acc)[4][4]) {
    BF8 bn[4];
    bn[0].u[0] = pkbf(buf[0].x, buf[1].x);
    bn[0].u[1] = pkbf(buf[2].x, buf[3].x);
    bn[0].u[2] = pkbf(buf[4].x, buf[5].x);
    bn[0].u[3] = pkbf(buf[6].x, buf[7].x);
    bn[1].u[0] = pkbf(buf[0].y, buf[1].y);
    bn[1].u[1] = pkbf(buf[2].y, buf[3].y);
    bn[1].u[2] = pkbf(buf[4].y, buf[5].y);
    bn[1].u[3] = pkbf(buf[6].y, buf[7].y);
    bn[2].u[0] = pkbf(buf[0].z, buf[1].z);
    bn[2].u[1] = pkbf(buf[2].z, buf[3].z);
    bn[2].u[2] = pkbf(buf[4].z, buf[5].z);
    bn[2].u[3] = pkbf(buf[6].z, buf[7].z);
    bn[3].u[0] = pkbf(buf[0].w, buf[1].w);
    bn[3].u[1] = pkbf(buf[2].w, buf[3].w);
    bn[3].u[2] = pkbf(buf[4].w, buf[5].w);
    bn[3].u[3] = pkbf(buf[6].w, buf[7].w);
#pragma unroll
    for (int m = 0; m < 4; ++m) {
        int gg = ((ks << 2) + lhi) ^ l7;                 // swizzled granule col
        bf16x8 af = *(const bf16x8*)&ws[m * 16 + l15][gg << 3];
        acc[m][0] = __builtin_amdgcn_mfma_f32_16x16x32_bf16(af, bn[0].v, acc[m][0], 0, 0, 0);
        acc[m][1] = __builtin_amdgcn_mfma_f32_16x16x32_bf16(af, bn[1].v, acc[m][1], 0, 0, 0);
        acc[m][2] = __builtin_amdgcn_mfma_f32_16x16x32_bf16(af, bn[2].v, acc[m][2], 0, 0, 0);
        acc[m][3] = __builtin_amdgcn_mfma_f32_16x16x32_bf16(af, bn[3].v, acc[m][3], 0, 0, 0);
    }
}

__global__ __launch_bounds__(256, 2) void compress_kernel(
    const float* __restrict__ x, const float* __restrict__ w_comp,
    unsigned short* __restrict__ comp)
{
    __shared__ short ws[CM][256];   // bf16 w, swizzled: granule g stored at g^(o&7)

    int tid = threadIdx.x;
    {   // stage w: thread t -> row o=t>>2, k-range (t&3)*64..+63 (coalesced)
        int o  = tid >> 2;
        int k0 = (tid & 3) << 6;
        const float* wr = w_comp + o * Cd + k0;
        int xr = o & 7;
#pragma unroll
        for (int gi = 0; gi < 8; ++gi) {
            float4 a = *(const float4*)(wr + gi * 8);
            float4 c = *(const float4*)(wr + gi * 8 + 4);
            BF8 g;
            g.u[0] = pkbf(a.x, a.y); g.u[1] = pkbf(a.z, a.w);
            g.u[2] = pkbf(c.x, c.y); g.u[3] = pkbf(c.z, c.w);
            int gg = ((k0 >> 3) + gi) ^ xr;
            *(bf16x8*)&ws[o][gg << 3] = g.v;
        }
    }
    __syncthreads();

    int lane = tid & 63;
    int wv   = tid >> 6;
    int blk  = blockIdx.x;            // 1024 blocks: [b(4)][s-tile(256)]
    int b    = blk >> 8;
    int s0   = ((blk & 255) << 8) + (wv << 6);   // wave: 64 s, all 64 o
    int l15  = lane & 15, lhi = lane >> 4, l7 = lane & 7;

    // lane's B data: x[b][ks*32 + lhi*8 + j][s0 + 4*l15 + {0..3}] (one float4)
    const float* px = x + (size_t)b * Cd * HW + (size_t)(lhi * 8) * HW + s0 + 4 * l15;

    f32x4 acc[4][4];
    f32x4 zz = {0.f, 0.f, 0.f, 0.f};
#pragma unroll
    for (int m = 0; m < 4; ++m)
#pragma unroll
        for (int n = 0; n < 4; ++n) acc[m][n] = zz;

    float4 pa[8], pb[8];
    loadB(px, 0, pa);
    for (int ks = 0; ks < 8; ks += 2) {
        loadB(px, ks + 1, pb);                       // prefetch odd step
        stepMFMA(pa, ws, ks, l15, lhi, l7, acc);     // consume even step
        if (ks + 2 < 8) loadB(px, ks + 2, pa);       // prefetch next even
        stepMFMA(pb, ws, ks + 1, l15, lhi, l7, acc); // consume odd step
    }

    // D layout (m89-verified): col = lane&15, row = (lane>>4)*4 + reg.
    // n-perm: col c of frag n -> s = s0 + 4c + n, so acc[m][0..3][r] are 4
    // adjacent s -> two packed bf16 u32 = one 8B store per (m,r).
    unsigned short* ob = comp + (size_t)b * CM * HW + s0 + 4 * l15;
#pragma unroll
    for (int m = 0; m < 4; ++m)
#pragma unroll
        for (int r = 0; r < 4; ++r) {
            uint2 pk;
            pk.x = pkbf(acc[m][0][r], acc[m][1][r]);
            pk.y = pkbf(acc[m][2][r], acc[m][3][r]);
            *(uint2*)&ob[(size_t)(m * 16 + lhi * 4 + r) * HW] = pk;
        }
}

// ---------------- Kernel B v3 (bf16 comp input): 3x3 conv + bias + softmax over 9 taps
// Block = 512 threads = 8 waves owns 4 consecutive h rows (wave = half-row,
// 2 positions/lane). R14 post-mortem: scalar-path weights regressed +42 us
// (s_load lgkm drain serializes each c-iter; ~81 live weight SGPRs wreck the
// schedule) -> REVERTED to the R13 wlds LDS-broadcast version (best: 257.4 us).
__global__ __launch_bounds__(512, 2) void kwgen_kernel(
    const unsigned short* __restrict__ comp, const float* __restrict__ w_gen,
    const float* __restrict__ b_gen, float* __restrict__ kw)
{
    __shared__ float wlds[CM][KK][12];
    // w_gen flat layout [t][c][3][3]: i = t*(CM*9) + c*9 + p
    for (int i = threadIdx.x; i < KK * CM * 9; i += 512) {
        int t = i / (CM * 9);
        int r = i - t * (CM * 9);
        int c = r / 9;
        int p = r - c * 9;
        wlds[c][t][p] = w_gen[i];
    }
    __syncthreads();

    int lane = threadIdx.x & 63;
    int wid  = threadIdx.x >> 6;      // 0..7
    int half = wid & 1;               // which half-row
    // XCD-chunked swizzle (T1, bijective: 256 % 8 == 0): consecutive decoded
    // blocks share an XCD -> halo comp rows hit the same L2.
    int blk  = (blockIdx.x & 7) * 32 + (blockIdx.x >> 3);   // 256 blocks: [b(4)][h-quad(64)]
    int b    = blk >> 6;
    int h    = ((blk & 63) << 2) + (wid >> 1);
    int w0   = (half << 7) + (lane << 1);     // first of 2 positions (even)
    bool hmv = h > 0, hpv = h < Hd - 1;

    float accv[KK][2];
#pragma unroll
    for (int t = 0; t < KK; ++t) { float bg = b_gen[t]; accv[t][0] = bg; accv[t][1] = bg; }

    const unsigned short* cb = comp + (size_t)b * CM * HW + h * Wd;
    for (int c = 0; c < CM; ++c) {
        const unsigned short* row = cb + (size_t)c * HW;
        const unsigned short* rm  = row - Wd;
        const unsigned short* rp  = row + Wd;
        uint32_t amu = hmv ? *(const uint32_t*)(rm + w0) : 0u;
        uint32_t acu = *(const uint32_t*)(row + w0);
        uint32_t apu = hpv ? *(const uint32_t*)(rp + w0) : 0u;
        float amx = bf2f(amu), amy = bf2f(amu >> 16);
        float acx = bf2f(acu), acy = bf2f(acu >> 16);
        float apx = bf2f(apu), apy = bf2f(apu >> 16);
        float Lm = __shfl_up(amy, 1), Lc = __shfl_up(acy, 1), Lp = __shfl_up(apy, 1);
        float Rm = __shfl_down(amx, 1), Rc = __shfl_down(acx, 1), Rp = __shfl_down(apx, 1);
        if (lane == 0) {
            if (w0 == 0) { Lm = 0.f; Lc = 0.f; Lp = 0.f; }
            else {
                Lm = hmv ? bf2f(rm[w0 - 1]) : 0.f;
                Lc = bf2f(row[w0 - 1]);
                Lp = hpv ? bf2f(rp[w0 - 1]) : 0.f;
            }
        }
        if (lane == 63) {
            int wr = w0 + 2;
            if (wr == Wd) { Rm = 0.f; Rc = 0.f; Rp = 0.f; }
            else {
                Rm = hmv ? bf2f(rm[wr]) : 0.f;
                Rc = bf2f(row[wr]);
                Rp = hpv ? bf2f(rp[wr]) : 0.f;
            }
        }
        float em[4] = {Lm, amx, amy, Rm};
        float ec[4] = {Lc, acx, acy, Rc};
        float ep[4] = {Lp, apx, apy, Rp};
#pragma unroll
        for (int t = 0; t < KK; ++t) {
            const float* wt = &wlds[c][t][0];
#pragma unroll
            for (int j = 0; j < 2; ++j) {
                float a = accv[t][j];
                a = fmaf(em[j],     wt[0], a);
                a = fmaf(em[j + 1], wt[1], a);
                a = fmaf(em[j + 2], wt[2], a);
                a = fmaf(ec[j],     wt[3], a);
                a = fmaf(ec[j + 1], wt[4], a);
                a = fmaf(ec[j + 2], wt[5], a);
                a = fmaf(ep[j],     wt[6], a);
                a = fmaf(ep[j + 1], wt[7], a);
                a = fmaf(ep[j + 2], wt[8], a);
                accv[t][j] = a;
            }
        }
    }
    // softmax over the 9 taps, per position
    float inv[2];
#pragma unroll
    for (int j = 0; j < 2; ++j) {
        float m = accv[0][j];
#pragma unroll
        for (int t = 1; t < KK; ++t) m = fmaxf(m, accv[t][j]);
        float sum = 0.f;
#pragma unroll
        for (int t = 0; t < KK; ++t) { accv[t][j] = __expf(accv[t][j] - m); sum += accv[t][j]; }
        inv[j] = 1.f / sum;
    }
    float* ob = kw + (size_t)b * KK * HW + h * Wd + w0;
#pragma unroll
    for (int t = 0; t < KK; ++t) {
        float2 v = make_float2(accv[t][0] * inv[0], accv[t][1] * inv[1]);
        *(float2*)(ob + (size_t)t * HW) = v;
    }
}

// ---------------- Kernel C: view-scramble gather + hamming renorm + reflect aggregation
// Wave per (b, h, cgroup); XCD-chunked swizzle (T1, R13 win, kept).
__global__ __launch_bounds__(256) void agg_kernel(
    const float* __restrict__ x, const float* __restrict__ kw,
    float* __restrict__ out)
{
    const float HAM[9] = {0.0064f, 0.08f, 0.0064f,
                          0.08f,   1.0f,  0.08f,
                          0.0064f, 0.08f, 0.0064f};
    int lane = threadIdx.x & 63;
    int wid  = threadIdx.x >> 6;
    // XCD-chunked swizzle (T1, bijective: 2048 % 8 == 0)
    int blk  = (blockIdx.x & 7) * 256 + (blockIdx.x >> 3);  // [b(4)][cg(8)][h4(64)]
    int h4 = blk & 63;
    int cg = (blk >> 6) & 7;
    int b  = blk >> 9;
    int h  = h4 * 4 + wid;
    int hm = (h == 0) ? 1 : h - 1;
    int hp = (h == Hd - 1) ? Hd - 2 : h + 1;

    // load + hamming-normalize the 4 positions' tap weights (view-scramble gather)
    float wv[4][9];
    {
        const float4* kv = (const float4*)(kw + (size_t)b * KK * HW
                                              + (size_t)h * (Wd * 9) + lane * 36);
        float t[36];
#pragma unroll
        for (int i = 0; i < 9; ++i) {
            float4 v = kv[i];
            t[i * 4 + 0] = v.x; t[i * 4 + 1] = v.y;
            t[i * 4 + 2] = v.z; t[i * 4 + 3] = v.w;
        }
#pragma unroll
        for (int j = 0; j < 4; ++j) {
            float s = 1e-8f;
#pragma unroll
            for (int p = 0; p < 9; ++p) { float u = t[j * 9 + p] * HAM[p]; wv[j][p] = u; s += u; }
            float inv = 1.f / s;
#pragma unroll
            for (int p = 0; p < 9; ++p) wv[j][p] *= inv;
        }
    }

    const float* xb = x + (size_t)b * Cd * HW;
    float* ob = out + (size_t)b * Cd * HW;
    int c0 = cg * CG;
    for (int c = c0; c < c0 + CG; ++c) {
        const float* xc0 = xb + (size_t)c * HW;
        float4 am = ((const float4*)(xc0 + hm * Wd))[lane];
        float4 ac = ((const float4*)(xc0 + h  * Wd))[lane];
        float4 ap = ((const float4*)(xc0 + hp * Wd))[lane];
        float Lm = __shfl_up(am.w, 1), Lc = __shfl_up(ac.w, 1), Lp = __shfl_up(ap.w, 1);
        float Rm = __shfl_down(am.x, 1), Rc = __shfl_down(ac.x, 1), Rp = __shfl_down(ap.x, 1);
        if (lane == 0)  { Lm = am.y; Lc = ac.y; Lp = ap.y; }   // reflect w=-1 -> w=1
        if (lane == 63) { Rm = am.z; Rc = ac.z; Rp = ap.z; }   // reflect w=256 -> w=254
        float em[6] = {Lm, am.x, am.y, am.z, am.w, Rm};
        float ec[6] = {Lc, ac.x, ac.y, ac.z, ac.w, Rc};
        float ep[6] = {Lp, ap.x, ap.y, ap.z, ap.w, Rp};
        float o4[4];
#pragma unroll
        for (int j = 0; j < 4; ++j) {
            float agg = em[j] * wv[j][0];
            agg = fmaf(em[j + 1], wv[j][1], agg);
            agg = fmaf(em[j + 2], wv[j][2], agg);
            agg = fmaf(ec[j],     wv[j][3], agg);
            agg = fmaf(ec[j + 1], wv[j][4], agg);
            agg = fmaf(ec[j + 2], wv[j][5], agg);
            agg = fmaf(ep[j],     wv[j][6], agg);
            agg = fmaf(ep[j + 1], wv[j][7], agg);
            agg = fmaf(ep[j + 2], wv[j][8], agg);
            o4[j] = 2.f * ec[j + 1] - agg;
        }
        float4 o = {o4[0], o4[1], o4[2], o4[3]};
        ((float4*)(ob + (size_t)c * HW + h * Wd))[lane] = o;
    }
}

extern "C" void kernel_launch(void* const* d_in, const int* in_sizes, int n_in,
                              void* d_out, int out_size, void* d_ws, size_t ws_size,
                              hipStream_t stream) {
    const float* x      = (const float*)d_in[0];
    const float* w_comp = (const float*)d_in[1];
    const float* w_gen  = (const float*)d_in[2];
    const float* b_gen  = (const float*)d_in[3];
    float* out  = (float*)d_out;
    unsigned short* comp = (unsigned short*)d_ws;              // 4*64*65536 bf16 = 32 MiB
    float* kw = (float*)((char*)d_ws + (size_t)Bd * CM * HW * sizeof(unsigned short));

    compress_kernel<<<1024, 256, 0, stream>>>(x, w_comp, comp);
    kwgen_kernel<<<256, 512, 0, stream>>>(comp, w_gen, b_gen, kw);
    agg_kernel<<<2048, 256, 0, stream>>>(x, kw, out);
}